// Round 10
// baseline (228.702 us; speedup 1.0000x reference)
//
#include <hip/hip_runtime.h>
#include <stdint.h>
#include <stddef.h>

// ---------- types ----------
typedef short s8v __attribute__((ext_vector_type(8)));   // 8 bf16 (4 VGPRs) MFMA A/B frag
typedef short s4v __attribute__((ext_vector_type(4)));   // 4 bf16
typedef float f4v __attribute__((ext_vector_type(4)));   // MFMA C/D frag

#define DEV static __device__ __forceinline__

// Problem constants: B=32 T=512 VOCAB=1024 D=256 H=256 O=1024 L=2
// Pipeline (5 dispatches):
//   wgemm : a0/a1/a2 from f32 inputs + U->bf16
//   gemm_x: Xc0 = x(f32) @ a0^T -> xc FRAG layout; 2-phase double-buffered staging
//   scan_fuse: layer-0 + Xc1 fused; LDS-only step barrier (stores never drained)
//   scan_rnn : layer-1; LDS-only step barrier
//   gemm_logsm: softmax_T(h1 @ a2^T); reg-prefetch staging, direct scattered out

DEV short f2b(float f) {
  union { float f; uint32_t u; } v; v.f = f;
  uint32_t u = v.u;
  uint32_t r = (u + 0x7fffu + ((u >> 16) & 1u)) >> 16;   // RNE
  return (short)(uint16_t)r;
}
DEV float b2f(short h) {
  union { uint32_t u; float f; } v; v.u = ((uint32_t)(uint16_t)h) << 16;
  return v.f;
}

DEV void gl_lds16(const void* g, void* l) {
  __builtin_amdgcn_global_load_lds(
      (__attribute__((address_space(1))) void*)(uintptr_t)(g),
      (__attribute__((address_space(3))) void*)(l), 16, 0, 0);
}

// LDS-only barrier: waits DS ops, NOT global stores (no vmcnt drain).
// Emitted-h / xc1 stores have no in-kernel readers -> they drain at s_endpgm.
DEV void lds_barrier() {
  __builtin_amdgcn_sched_barrier(0);
  asm volatile("s_waitcnt lgkmcnt(0)" ::: "memory");
  __builtin_amdgcn_s_barrier();
  __builtin_amdgcn_sched_barrier(0);
}

// conflict-free hT layout: hT[s][k] stored at [kb][q][s][j], k = kb*32 + q*8 + j.
DEV int hoff(int s, int k) {
  return ((k >> 5) << 9) + (((k >> 3) & 3) << 7) + (s << 3) + (k & 7);
}

// ---------- weight-product GEMMs straight from f32 + U bf16 convert ----------
DEV void wgemm_body(const float* __restrict__ Af, const float* __restrict__ Bsrc,
                    short* __restrict__ C, int lda, int ldbs, int ldc,
                    int m0, int n0, int tid, short* As, float* Bf) {
  const int w = tid >> 6, lane = tid & 63, quad = lane >> 4, sid = lane & 15;
  const int wm = (w >> 1) * 64, wn = (w & 1) * 64;

  f4v acc[4][4];
#pragma unroll
  for (int i = 0; i < 4; ++i)
#pragma unroll
    for (int j = 0; j < 4; ++j) acc[i][j] = (f4v){0.f, 0.f, 0.f, 0.f};

  for (int k0 = 0; k0 < 256; k0 += 64) {
#pragma unroll
    for (int q = 0; q < 8; ++q) {
      int lin = q * 256 + tid;
      int kr = lin >> 5, nc = (lin & 31) << 2;
      gl_lds16(Bsrc + (size_t)(k0 + kr) * ldbs + n0 + nc, &Bf[lin << 2]);
    }
#pragma unroll
    for (int q = 0; q < 4; ++q) {
      int lin = q * 256 + tid;
      int row = lin >> 3, kc = (lin & 7) << 3;
      const float* ap = Af + (size_t)(m0 + row) * lda + k0 + kc;
      float4 v0 = *(const float4*)ap;
      float4 v1 = *(const float4*)(ap + 4);
      s8v p;
      p[0] = f2b(v0.x); p[1] = f2b(v0.y); p[2] = f2b(v0.z); p[3] = f2b(v0.w);
      p[4] = f2b(v1.x); p[5] = f2b(v1.y); p[6] = f2b(v1.z); p[7] = f2b(v1.w);
      *(s8v*)&As[row * 72 + kc] = p;
    }
    __syncthreads();
#pragma unroll
    for (int kb = 0; kb < 2; ++kb) {
      s8v af[4], bf[4];
#pragma unroll
      for (int mt = 0; mt < 4; ++mt)
        af[mt] = *(const s8v*)&As[(wm + 16 * mt + sid) * 72 + kb * 32 + quad * 8];
#pragma unroll
      for (int nt = 0; nt < 4; ++nt) {
        s8v b;
#pragma unroll
        for (int j = 0; j < 8; ++j)
          b[j] = f2b(Bf[(kb * 32 + quad * 8 + j) * 128 + wn + 16 * nt + sid]);
        bf[nt] = b;
      }
#pragma unroll
      for (int mt = 0; mt < 4; ++mt)
#pragma unroll
        for (int nt = 0; nt < 4; ++nt)
          acc[mt][nt] = __builtin_amdgcn_mfma_f32_16x16x32_bf16(af[mt], bf[nt], acc[mt][nt], 0, 0, 0);
    }
    __syncthreads();
  }
#pragma unroll
  for (int mt = 0; mt < 4; ++mt)
#pragma unroll
    for (int r = 0; r < 4; ++r) {
      int gm = m0 + wm + 16 * mt + 4 * quad + r;
      size_t ro = (size_t)gm * ldc;
#pragma unroll
      for (int nt = 0; nt < 4; ++nt)
        C[ro + n0 + wn + 16 * nt + sid] = f2b(acc[mt][nt][r]);
    }
}

__global__ __launch_bounds__(256) void wgemm(const float* __restrict__ wemb,
                                             const float* __restrict__ wf,
                                             const float* __restrict__ vfp,
                                             const float* __restrict__ wout,
                                             const float* __restrict__ ufp,
                                             short* __restrict__ a0,
                                             short* __restrict__ a1,
                                             short* __restrict__ a2,
                                             short* __restrict__ ub) {
  __shared__ __align__(16) short As[128 * 72];   // 18 KB
  __shared__ __align__(16) float Bf[64 * 128];   // 32 KB
  const int blk = blockIdx.x, tid = threadIdx.x;
  if (blk < 16) {          // a0 = W0 @ Wemb : [256,1024], 2x8 tiles
    wgemm_body(wf, wemb, a0, 256, 1024, 1024,
               (blk >> 3) * 128, (blk & 7) * 128, tid, As, Bf);
  } else if (blk < 20) {   // a1 = W1 @ V0 : [256,256], 2x2 tiles
    int b = blk - 16;
    wgemm_body(wf + 65536, vfp, a1, 256, 256, 256,
               (b >> 1) * 128, (b & 1) * 128, tid, As, Bf);
  } else if (blk < 36) {   // a2 = Wout @ V1 : [1024,256], 8x2 tiles
    int b = blk - 20;
    wgemm_body(wout, vfp + 65536, a2, 256, 256, 256,
               (b >> 1) * 128, (b & 1) * 128, tid, As, Bf);
  } else {                 // blk 36..39: U (2 layers, 512 KB f32) -> bf16 once
    int b = blk - 36;
    const float* src = ufp + (size_t)b * 32768;
    short* dst = ub + (size_t)b * 32768;
#pragma unroll 4
    for (int i = tid; i < 8192; i += 256) {
      float4 v = ((const float4*)src)[i];
      s4v q; q.x = f2b(v.x); q.y = f2b(v.y); q.z = f2b(v.z); q.w = f2b(v.w);
      ((s4v*)dst)[i] = q;
    }
  }
}

// ---------- Xc0 = x(f32) @ A0^T -> xc frag layout, 2-phase double-buffered ----------
// STAGE(t+1) issued BEFORE compute(t): global_load_lds gets the whole MFMA phase
// in flight before the barrier drains it (T3-minimal; was stage->barrier->compute
// with zero slack). LDS 2x(4.5+32) = 73 KB -> still 2 blocks/CU.
__global__ __launch_bounds__(256, 2) void gemm_x(const float* __restrict__ Xf,
                                                 const short* __restrict__ Bw,
                                                 short* __restrict__ C) {
  __shared__ __align__(16) short As[2][32 * 72];
  __shared__ __align__(16) short Bs[2][256 * 64];
  const int tid = threadIdx.x;
  const int w = tid >> 6, lane = tid & 63, quad = lane >> 4, sid = lane & 15;
  const int g = blockIdx.x >> 8, tp = blockIdx.x & 255;
  const int wn = w * 64;

  const int arow = tid >> 3, akc = (tid & 7) << 3;
  const int am = (g * 16 + (arow & 15)) * 512 + 2 * tp + (arow >> 4);
  const float* aptr = &Xf[(size_t)am * 1024 + akc];

#define GX_STAGE(buf, k0)                                                     \
  {                                                                           \
    _Pragma("unroll")                                                         \
    for (int q = 0; q < 8; ++q) {                                             \
      int lin = q * 256 + tid;                                                \
      gl_lds16(Bw + (size_t)(lin >> 3) * 1024 + (k0) + ((lin & 7) << 3),      \
               &Bs[buf][lin << 3]);                                           \
    }                                                                         \
    const float* ap = aptr + (k0);                                            \
    float4 v0 = *(const float4*)ap;                                           \
    float4 v1 = *(const float4*)(ap + 4);                                     \
    s8v p;                                                                    \
    p[0] = f2b(v0.x); p[1] = f2b(v0.y); p[2] = f2b(v0.z); p[3] = f2b(v0.w);   \
    p[4] = f2b(v1.x); p[5] = f2b(v1.y); p[6] = f2b(v1.z); p[7] = f2b(v1.w);   \
    *(s8v*)&As[buf][arow * 72 + akc] = p;                                     \
  }

  f4v acc[2][4];
#pragma unroll
  for (int i = 0; i < 2; ++i)
#pragma unroll
    for (int j = 0; j < 4; ++j) acc[i][j] = (f4v){0.f, 0.f, 0.f, 0.f};

  GX_STAGE(0, 0);
  __syncthreads();
  for (int it = 0; it < 16; ++it) {
    const int cur = it & 1;
    if (it < 15) GX_STAGE(cur ^ 1, (it + 1) * 64);
#pragma unroll
    for (int kb = 0; kb < 2; ++kb) {
      s8v af[2], bf[4];
#pragma unroll
      for (int mt = 0; mt < 2; ++mt)
        af[mt] = *(const s8v*)&As[cur][(16 * mt + sid) * 72 + kb * 32 + quad * 8];
#pragma unroll
      for (int nt = 0; nt < 4; ++nt)
        bf[nt] = *(const s8v*)&Bs[cur][(wn + 16 * nt + sid) * 64 + kb * 32 + quad * 8];
#pragma unroll
      for (int mt = 0; mt < 2; ++mt)
#pragma unroll
        for (int nt = 0; nt < 4; ++nt)
          acc[mt][nt] = __builtin_amdgcn_mfma_f32_16x16x32_bf16(af[mt], bf[nt], acc[mt][nt], 0, 0, 0);
    }
    __syncthreads();
  }
#undef GX_STAGE

  // epilogue: stage C[lr][n] into Ls (pitch 264), then frag-layout contiguous write
  short* Ls = &Bs[0][0];
#pragma unroll
  for (int mt = 0; mt < 2; ++mt)
#pragma unroll
    for (int nt = 0; nt < 4; ++nt) {
      int n = wn + 16 * nt + sid;
#pragma unroll
      for (int r = 0; r < 4; ++r)
        Ls[(16 * mt + 4 * quad + r) * 264 + n] = f2b(acc[mt][nt][r]);
    }
  __syncthreads();
  {
    const size_t obase = (size_t)((g << 9) + 2 * tp) * 4096;
#pragma unroll
    for (int h = 0; h < 2; ++h) {
      int q = h * 256 + tid;            // 0..511
      int tl = q >> 8, q16 = q & 255;
      int ch = q16 >> 3, qq = q16 & 7;
      s4v lo = *(const s4v*)&Ls[(tl * 16 + 2 * qq) * 264 + ch * 4];
      s4v hi = *(const s4v*)&Ls[(tl * 16 + 2 * qq + 1) * 264 + ch * 4];
      s8v v;
      v[0] = lo.x; v[1] = lo.y; v[2] = lo.z; v[3] = lo.w;
      v[4] = hi.x; v[5] = hi.y; v[6] = hi.z; v[7] = hi.w;
      *(s8v*)&C[obase + (size_t)tl * 4096 + q16 * 8] = v;
    }
  }
}

// ---------- layer-0 scan fused with Xc1 = h0 @ A1^T ----------
// LDS-only step barrier: XcOut stores are never drained mid-scan.
__global__ __launch_bounds__(256, 1) void scan_fuse(const short* __restrict__ Ub,
                                                    const short* __restrict__ A1b,
                                                    const short* __restrict__ XcIn,
                                                    short* __restrict__ XcOut,
                                                    const float* __restrict__ hinit) {
  constexpr int CL = 4, WU = 12, NC = 128;
  __shared__ __align__(16) short hT[2][4096];
  const int tid = threadIdx.x;
  const int w = tid >> 6, lane = tid & 63, quad = lane >> 4, sid = lane & 15;
  const int c = blockIdx.x & (NC - 1);
  const int g = blockIdx.x >> 7;
  const int laneoff = quad * 64 + sid * 4;

  s8v uf[4][8], vf[4][8];
#pragma unroll
  for (int mt = 0; mt < 4; ++mt)
#pragma unroll
    for (int kb = 0; kb < 8; ++kb) {
      int i = 64 * w + 16 * mt + sid;
      int k = 32 * kb + quad * 8;
      uf[mt][kb] = *(const s8v*)&Ub[i * 256 + k];
      vf[mt][kb] = *(const s8v*)&A1b[i * 256 + k];
    }

  const int t0 = (c * CL <= WU) ? 0 : c * CL - WU;
  const int t1 = (c + 1) * CL;

  for (int idx = tid; idx < 4096; idx += 256) {
    int s = idx >> 8, i = idx & 255;
    hT[0][hoff(s, i)] = (t0 == 0) ? f2b(hinit[i]) : (short)0;
  }
  __syncthreads();

  s4v xcn[4];
  {
    const size_t xb = (size_t)((g << 9) + t0) * 4096 + 1024 * w + laneoff;
#pragma unroll
    for (int mt = 0; mt < 4; ++mt)
      xcn[mt] = *(const s4v*)&XcIn[xb + 256 * mt];
  }

  int pr = 0;
  for (int t = t0; t <= t1; ++t) {
    s8v bf[8];
#pragma unroll
    for (int kb = 0; kb < 8; ++kb)
      bf[kb] = *(const s8v*)&hT[pr][kb * 512 + quad * 128 + sid * 8];
    const bool doh = (t < t1);
    s4v xcc[4];
    if (doh) {
#pragma unroll
      for (int mt = 0; mt < 4; ++mt) xcc[mt] = xcn[mt];
    }
    if (t + 1 < t1) {   // issue next step's xc loads (hidden under MFMA passes)
      const size_t xb = (size_t)((g << 9) + t + 1) * 4096 + 1024 * w + laneoff;
#pragma unroll
      for (int mt = 0; mt < 4; ++mt)
        xcn[mt] = *(const s4v*)&XcIn[xb + 256 * mt];
    }

    if (t > c * CL) {  // emit xc1_{t-1} = h_{t-1} @ A1^T (owned, warmed rows only)
      f4v ax[4];
#pragma unroll
      for (int mt = 0; mt < 4; ++mt) ax[mt] = (f4v){0.f, 0.f, 0.f, 0.f};
#pragma unroll
      for (int kb = 0; kb < 8; ++kb)
#pragma unroll
        for (int mt = 0; mt < 4; ++mt)
          ax[mt] = __builtin_amdgcn_mfma_f32_16x16x32_bf16(vf[mt][kb], bf[kb], ax[mt], 0, 0, 0);
      const size_t ob = (size_t)((g << 9) + (t - 1)) * 4096 + 1024 * w + laneoff;
#pragma unroll
      for (int mt = 0; mt < 4; ++mt) {
        s4v p; p.x = f2b(ax[mt].x); p.y = f2b(ax[mt].y);
        p.z = f2b(ax[mt].z); p.w = f2b(ax[mt].w);
        *(s4v*)&XcOut[ob + 256 * mt] = p;
      }
    }

    if (doh) {
      f4v acc[4];
#pragma unroll
      for (int mt = 0; mt < 4; ++mt) acc[mt] = (f4v){0.f, 0.f, 0.f, 0.f};
#pragma unroll
      for (int kb = 0; kb < 8; ++kb)
#pragma unroll
        for (int mt = 0; mt < 4; ++mt)
          acc[mt] = __builtin_amdgcn_mfma_f32_16x16x32_bf16(uf[mt][kb], bf[kb], acc[mt], 0, 0, 0);
#pragma unroll
      for (int mt = 0; mt < 4; ++mt) {
        int k0 = 64 * w + 16 * mt + 4 * quad;
        f4v v = acc[mt];
        v.x += b2f(xcc[mt].x); v.y += b2f(xcc[mt].y);
        v.z += b2f(xcc[mt].z); v.w += b2f(xcc[mt].w);
        s4v p; p.x = f2b(v.x); p.y = f2b(v.y); p.z = f2b(v.z); p.w = f2b(v.w);
        *(s4v*)&hT[pr ^ 1][hoff(sid, k0)] = p;
      }
    }
    pr ^= 1;
    lds_barrier();
  }
}

// ---------- chunked recurrence scan (layer 1) ----------
// LDS-only step barrier: hbuf stores never drained mid-scan.
__global__ __launch_bounds__(256, 2) void scan_rnn(const short* __restrict__ Ub,
                                                   const short* __restrict__ XcT,
                                                   short* __restrict__ hbuf,
                                                   const float* __restrict__ hinit) {
  constexpr int CL = 2, WU = 12, NC = 256;
  __shared__ __align__(16) short hT[2][4096];
  const int tid = threadIdx.x;
  const int w = tid >> 6, lane = tid & 63, quad = lane >> 4, sid = lane & 15;
  const int c = blockIdx.x & (NC - 1);
  const int g = blockIdx.x >> 8;
  const int laneoff = quad * 64 + sid * 4;

  s8v uf[4][8];
#pragma unroll
  for (int mt = 0; mt < 4; ++mt)
#pragma unroll
    for (int kb = 0; kb < 8; ++kb) {
      int i = 64 * w + 16 * mt + sid;
      int k = 32 * kb + quad * 8;
      uf[mt][kb] = *(const s8v*)&Ub[i * 256 + k];
    }

  const int t0 = (c * CL <= WU) ? 0 : c * CL - WU;
  const int t1 = (c + 1) * CL;

  for (int idx = tid; idx < 4096; idx += 256) {
    int s = idx >> 8, i = idx & 255;
    hT[0][hoff(s, i)] = (t0 == 0) ? f2b(hinit[i]) : (short)0;
  }
  __syncthreads();

  s4v xcn[4];
  {
    const size_t xb = (size_t)((g << 9) + t0) * 4096 + 1024 * w + laneoff;
#pragma unroll
    for (int mt = 0; mt < 4; ++mt)
      xcn[mt] = *(const s4v*)&XcT[xb + 256 * mt];
  }

  int pr = 0;
  for (int t = t0; t < t1; ++t) {
    s8v bf[8];
#pragma unroll
    for (int kb = 0; kb < 8; ++kb)
      bf[kb] = *(const s8v*)&hT[pr][kb * 512 + quad * 128 + sid * 8];
    s4v xcc[4];
#pragma unroll
    for (int mt = 0; mt < 4; ++mt) xcc[mt] = xcn[mt];
    if (t + 1 < t1) {
      const size_t xb = (size_t)((g << 9) + t + 1) * 4096 + 1024 * w + laneoff;
#pragma unroll
      for (int mt = 0; mt < 4; ++mt)
        xcn[mt] = *(const s4v*)&XcT[xb + 256 * mt];
    }

    f4v acc[4];
#pragma unroll
    for (int mt = 0; mt < 4; ++mt) acc[mt] = (f4v){0.f, 0.f, 0.f, 0.f};
#pragma unroll
    for (int kb = 0; kb < 8; ++kb)
#pragma unroll
      for (int mt = 0; mt < 4; ++mt)
        acc[mt] = __builtin_amdgcn_mfma_f32_16x16x32_bf16(uf[mt][kb], bf[kb], acc[mt], 0, 0, 0);

    const bool emit = (t >= c * CL);
    const size_t xbase = ((size_t)((g << 9) + t) * 16 + sid) * 256;
#pragma unroll
    for (int mt = 0; mt < 4; ++mt) {
      int k0 = 64 * w + 16 * mt + 4 * quad;
      f4v v = acc[mt];
      v.x += b2f(xcc[mt].x); v.y += b2f(xcc[mt].y);
      v.z += b2f(xcc[mt].z); v.w += b2f(xcc[mt].w);
      s4v p; p.x = f2b(v.x); p.y = f2b(v.y); p.z = f2b(v.z); p.w = f2b(v.w);
      *(s4v*)&hT[pr ^ 1][hoff(sid, k0)] = p;
      if (emit) *(s4v*)&hbuf[xbase + k0] = p;
    }
    pr ^= 1;
    lds_barrier();
  }
}

// ---------- fused logits GEMM + softmax over T ----------
// T14 reg-prefetch staging: loads(k+1) issued after the stage barrier, in flight
// under the MFMA phase. Epilogue: direct scattered f32 stores (measured best).
__global__ __launch_bounds__(256, 2) void gemm_logsm(const short* __restrict__ A,
                                                     const short* __restrict__ Bw,
                                                     float* __restrict__ out) {
  __shared__ __align__(16) short As[512 * 40];   // [t][k-local 32, pitch 40]
  __shared__ __align__(16) short Bs[64 * 32];
  __shared__ float2 red[4][64];
  const int tid = threadIdx.x;
  const int w = tid >> 6, lane = tid & 63, quad = lane >> 4, sid = lane & 15;
  const int b = blockIdx.x & 31, ot = blockIdx.x >> 5;
  const int g = b >> 4, si = b & 15;

  f4v acc[8][4];
#pragma unroll
  for (int i = 0; i < 8; ++i)
#pragma unroll
    for (int j = 0; j < 4; ++j) acc[i][j] = (f4v){0.f, 0.f, 0.f, 0.f};

  // per-thread staging addresses (fixed across k-steps)
  const int at = (tid * 4 + 1024 * 0) >> 2;  // silence unused warn pattern
  (void)at;
  const int brow = tid & 63, bkch = tid >> 6;
  const short* bptr = Bw + (size_t)(ot * 64 + brow) * 256 + bkch * 8;

  s8v va[8], vb;
#pragma unroll
  for (int q = 0; q < 8; ++q) {
    int lin = q * 256 + tid;
    int t = lin >> 2, kch = lin & 3;
    size_t ar = ((size_t)(g * 512 + t) * 16 + si) * 256;
    va[q] = *(const s8v*)(A + ar + kch * 8);
  }
  vb = *(const s8v*)bptr;

  for (int it = 0; it < 8; ++it) {
    // ds_write staged regs
#pragma unroll
    for (int q = 0; q < 8; ++q) {
      int lin = q * 256 + tid;
      int t = lin >> 2, kch = lin & 3;
      *(s8v*)&As[t * 40 + kch * 8] = va[q];
    }
    *(s8v*)&Bs[tid << 3] = vb;
    __syncthreads();
    if (it < 7) {   // issue next k-step's loads; land during the MFMA phase
      int k0n = (it + 1) * 32;
#pragma unroll
      for (int q = 0; q < 8; ++q) {
        int lin = q * 256 + tid;
        int t = lin >> 2, kch = lin & 3;
        size_t ar = ((size_t)(g * 512 + t) * 16 + si) * 256;
        va[q] = *(const s8v*)(A + ar + k0n + kch * 8);
      }
      vb = *(const s8v*)(bptr + k0n);
    }
    s8v bf[4];
#pragma unroll
    for (int nt = 0; nt < 4; ++nt)
      bf[nt] = *(const s8v*)&Bs[(quad * 64 + 16 * nt + sid) * 8];
#pragma unroll
    for (int mt = 0; mt < 8; ++mt) {
      s8v af = *(const s8v*)&As[(128 * w + 16 * mt + sid) * 40 + quad * 8];
#pragma unroll
      for (int nt = 0; nt < 4; ++nt)
        acc[mt][nt] = __builtin_amdgcn_mfma_f32_16x16x32_bf16(af, bf[nt], acc[mt][nt], 0, 0, 0);
    }
    __syncthreads();
  }

  // softmax stats over t per column (16nt+sid)
  float Mv[4], Iv[4];
#pragma unroll
  for (int nt = 0; nt < 4; ++nt) {
    float m = -3.0e38f;
#pragma unroll
    for (int mt = 0; mt < 8; ++mt)
#pragma unroll
      for (int r = 0; r < 4; ++r) m = fmaxf(m, acc[mt][nt][r]);
    float sum = 0.f;
#pragma unroll
    for (int mt = 0; mt < 8; ++mt)
#pragma unroll
      for (int r = 0; r < 4; ++r) sum += __expf(acc[mt][nt][r] - m);
#pragma unroll
    for (int d = 16; d < 64; d <<= 1) {
      float om = __shfl_xor(m, d, 64);
      float os = __shfl_xor(sum, d, 64);
      float nm = fmaxf(m, om);
      sum = sum * __expf(m - nm) + os * __expf(om - nm);
      m = nm;
    }
    if (quad == 0) red[w][16 * nt + sid] = (float2){m, sum};
  }
  __syncthreads();
#pragma unroll
  for (int nt = 0; nt < 4; ++nt) {
    float M = -3.0e38f, S = 0.f;
#pragma unroll
    for (int ww = 0; ww < 4; ++ww) {
      float2 r2 = red[ww][16 * nt + sid];
      float nm = fmaxf(M, r2.x);
      S = S * __expf(M - nm) + r2.y * __expf(r2.x - nm);
      M = nm;
    }
    Mv[nt] = M;
    Iv[nt] = 1.0f / S;
  }

  // direct scattered out-write (no barriers, no LDS round-trip)
  const size_t cbase = (size_t)b * 524288 + ot * 64 + sid;
#pragma unroll
  for (int nt = 0; nt < 4; ++nt) {
    const size_t cb = cbase + 16 * nt;
#pragma unroll
    for (int mt = 0; mt < 8; ++mt)
#pragma unroll
      for (int r = 0; r < 4; ++r) {
        int t = 128 * w + 16 * mt + 4 * quad + r;
        out[cb + (size_t)t * 1024] = __expf(acc[mt][nt][r] - Mv[nt]) * Iv[nt];
      }
  }
}

// ---------- host ----------
extern "C" void kernel_launch(void* const* d_in, const int* in_sizes, int n_in,
                              void* d_out, int out_size, void* d_ws, size_t ws_size,
                              hipStream_t stream) {
  (void)in_sizes; (void)n_in; (void)out_size; (void)ws_size;
  const float* xf   = (const float*)d_in[0];
  const float* hs   = (const float*)d_in[1];
  const float* wemb = (const float*)d_in[2];
  const float* wf   = (const float*)d_in[3];
  const float* ufp  = (const float*)d_in[4];
  const float* vfp  = (const float*)d_in[5];
  const float* wout = (const float*)d_in[6];

  char* ws = (char*)d_ws;
  short* hbuf = (short*)(ws);              // 8,388,608 B  layer-1 h, row layout
  short* xcT0 = (short*)(ws + 8388608);    // 8,388,608 B  Xc0 frag layout
  short* xcT1 = (short*)(ws + 16777216);   // 8,388,608 B  Xc1 frag layout
  short* a0   = (short*)(ws + 25165824);   //   524,288 B  W0@Wemb  [256,1024]
  short* a1   = (short*)(ws + 25690112);   //   131,072 B  W1@V0    [256,256]
  short* a2   = (short*)(ws + 25821184);   //   524,288 B  Wout@V1  [1024,256]
  short* ub   = (short*)(ws + 26345472);   //   262,144 B  U bf16 (2 layers)

  // a0/a1/a2 from f32 inputs + U -> bf16
  wgemm<<<40, 256, 0, stream>>>(wemb, wf, vfp, wout, ufp, a0, a1, a2, ub);

  // Xc0 = x(f32) @ a0^T -> frag layout (2-phase pipelined)
  gemm_x<<<512, 256, 0, stream>>>(xf, a0, xcT0);

  // layer-0 scan, Xc1 = h0 @ a1^T fused (frag in/out)
  scan_fuse<<<256, 256, 0, stream>>>(ub, a1, xcT0, xcT1, hs);

  // layer-1 scan (frag in, row out)
  scan_rnn<<<512, 256, 0, stream>>>(ub + 65536, xcT1, hbuf, hs + 256);

  // probs = softmax_T(h1 @ a2^T), fused, reg-prefetch staging
  gemm_logsm<<<512, 256, 0, stream>>>(hbuf, a2, (float*)d_out);
}

// Round 11
// 227.252 us; speedup vs baseline: 1.0064x; 1.0064x over previous
//
#include <hip/hip_runtime.h>
#include <stdint.h>
#include <stddef.h>

// ---------- types ----------
typedef short s8v __attribute__((ext_vector_type(8)));   // 8 bf16 (4 VGPRs) MFMA A/B frag
typedef short s4v __attribute__((ext_vector_type(4)));   // 4 bf16
typedef float f4v __attribute__((ext_vector_type(4)));   // MFMA C/D frag

#define DEV static __device__ __forceinline__

// Problem constants: B=32 T=512 VOCAB=1024 D=256 H=256 O=1024 L=2
// Pipeline (5 dispatches):
//   wgemm : a0/a1/a2 from f32 inputs + U->bf16
//   gemm_x: Xc0 = x(f32) @ a0^T -> xc FRAG layout; 2-phase double-buffered staging
//   scan_fuse: layer-0 + Xc1 fused; 8-wave SPLIT (waves 0-3: U0 h-update,
//              waves 4-7: A1 xc1-emit) -> per-step MFMA critical path halved
//   scan_rnn : layer-1; LDS-only step barrier
//   gemm_logsm: softmax_T(h1 @ a2^T); reg-prefetch staging, direct scattered out

DEV short f2b(float f) {
  union { float f; uint32_t u; } v; v.f = f;
  uint32_t u = v.u;
  uint32_t r = (u + 0x7fffu + ((u >> 16) & 1u)) >> 16;   // RNE
  return (short)(uint16_t)r;
}
DEV float b2f(short h) {
  union { uint32_t u; float f; } v; v.u = ((uint32_t)(uint16_t)h) << 16;
  return v.f;
}

DEV void gl_lds16(const void* g, void* l) {
  __builtin_amdgcn_global_load_lds(
      (__attribute__((address_space(1))) void*)(uintptr_t)(g),
      (__attribute__((address_space(3))) void*)(l), 16, 0, 0);
}

// LDS-only barrier: waits DS ops, NOT global stores (no vmcnt drain).
DEV void lds_barrier() {
  __builtin_amdgcn_sched_barrier(0);
  asm volatile("s_waitcnt lgkmcnt(0)" ::: "memory");
  __builtin_amdgcn_s_barrier();
  __builtin_amdgcn_sched_barrier(0);
}

// conflict-free hT layout: hT[s][k] stored at [kb][q][s][j], k = kb*32 + q*8 + j.
DEV int hoff(int s, int k) {
  return ((k >> 5) << 9) + (((k >> 3) & 3) << 7) + (s << 3) + (k & 7);
}

// ---------- weight-product GEMMs straight from f32 + U bf16 convert ----------
DEV void wgemm_body(const float* __restrict__ Af, const float* __restrict__ Bsrc,
                    short* __restrict__ C, int lda, int ldbs, int ldc,
                    int m0, int n0, int tid, short* As, float* Bf) {
  const int w = tid >> 6, lane = tid & 63, quad = lane >> 4, sid = lane & 15;
  const int wm = (w >> 1) * 64, wn = (w & 1) * 64;

  f4v acc[4][4];
#pragma unroll
  for (int i = 0; i < 4; ++i)
#pragma unroll
    for (int j = 0; j < 4; ++j) acc[i][j] = (f4v){0.f, 0.f, 0.f, 0.f};

  for (int k0 = 0; k0 < 256; k0 += 64) {
#pragma unroll
    for (int q = 0; q < 8; ++q) {
      int lin = q * 256 + tid;
      int kr = lin >> 5, nc = (lin & 31) << 2;
      gl_lds16(Bsrc + (size_t)(k0 + kr) * ldbs + n0 + nc, &Bf[lin << 2]);
    }
#pragma unroll
    for (int q = 0; q < 4; ++q) {
      int lin = q * 256 + tid;
      int row = lin >> 3, kc = (lin & 7) << 3;
      const float* ap = Af + (size_t)(m0 + row) * lda + k0 + kc;
      float4 v0 = *(const float4*)ap;
      float4 v1 = *(const float4*)(ap + 4);
      s8v p;
      p[0] = f2b(v0.x); p[1] = f2b(v0.y); p[2] = f2b(v0.z); p[3] = f2b(v0.w);
      p[4] = f2b(v1.x); p[5] = f2b(v1.y); p[6] = f2b(v1.z); p[7] = f2b(v1.w);
      *(s8v*)&As[row * 72 + kc] = p;
    }
    __syncthreads();
#pragma unroll
    for (int kb = 0; kb < 2; ++kb) {
      s8v af[4], bf[4];
#pragma unroll
      for (int mt = 0; mt < 4; ++mt)
        af[mt] = *(const s8v*)&As[(wm + 16 * mt + sid) * 72 + kb * 32 + quad * 8];
#pragma unroll
      for (int nt = 0; nt < 4; ++nt) {
        s8v b;
#pragma unroll
        for (int j = 0; j < 8; ++j)
          b[j] = f2b(Bf[(kb * 32 + quad * 8 + j) * 128 + wn + 16 * nt + sid]);
        bf[nt] = b;
      }
#pragma unroll
      for (int mt = 0; mt < 4; ++mt)
#pragma unroll
        for (int nt = 0; nt < 4; ++nt)
          acc[mt][nt] = __builtin_amdgcn_mfma_f32_16x16x32_bf16(af[mt], bf[nt], acc[mt][nt], 0, 0, 0);
    }
    __syncthreads();
  }
#pragma unroll
  for (int mt = 0; mt < 4; ++mt)
#pragma unroll
    for (int r = 0; r < 4; ++r) {
      int gm = m0 + wm + 16 * mt + 4 * quad + r;
      size_t ro = (size_t)gm * ldc;
#pragma unroll
      for (int nt = 0; nt < 4; ++nt)
        C[ro + n0 + wn + 16 * nt + sid] = f2b(acc[mt][nt][r]);
    }
}

__global__ __launch_bounds__(256) void wgemm(const float* __restrict__ wemb,
                                             const float* __restrict__ wf,
                                             const float* __restrict__ vfp,
                                             const float* __restrict__ wout,
                                             const float* __restrict__ ufp,
                                             short* __restrict__ a0,
                                             short* __restrict__ a1,
                                             short* __restrict__ a2,
                                             short* __restrict__ ub) {
  __shared__ __align__(16) short As[128 * 72];   // 18 KB
  __shared__ __align__(16) float Bf[64 * 128];   // 32 KB
  const int blk = blockIdx.x, tid = threadIdx.x;
  if (blk < 16) {          // a0 = W0 @ Wemb : [256,1024], 2x8 tiles
    wgemm_body(wf, wemb, a0, 256, 1024, 1024,
               (blk >> 3) * 128, (blk & 7) * 128, tid, As, Bf);
  } else if (blk < 20) {   // a1 = W1 @ V0 : [256,256], 2x2 tiles
    int b = blk - 16;
    wgemm_body(wf + 65536, vfp, a1, 256, 256, 256,
               (b >> 1) * 128, (b & 1) * 128, tid, As, Bf);
  } else if (blk < 36) {   // a2 = Wout @ V1 : [1024,256], 8x2 tiles
    int b = blk - 20;
    wgemm_body(wout, vfp + 65536, a2, 256, 256, 256,
               (b >> 1) * 128, (b & 1) * 128, tid, As, Bf);
  } else {                 // blk 36..39: U (2 layers, 512 KB f32) -> bf16 once
    int b = blk - 36;
    const float* src = ufp + (size_t)b * 32768;
    short* dst = ub + (size_t)b * 32768;
#pragma unroll 4
    for (int i = tid; i < 8192; i += 256) {
      float4 v = ((const float4*)src)[i];
      s4v q; q.x = f2b(v.x); q.y = f2b(v.y); q.z = f2b(v.z); q.w = f2b(v.w);
      ((s4v*)dst)[i] = q;
    }
  }
}

// ---------- Xc0 = x(f32) @ A0^T -> xc frag layout, 2-phase double-buffered ----------
__global__ __launch_bounds__(256, 2) void gemm_x(const float* __restrict__ Xf,
                                                 const short* __restrict__ Bw,
                                                 short* __restrict__ C) {
  __shared__ __align__(16) short As[2][32 * 72];
  __shared__ __align__(16) short Bs[2][256 * 64];
  const int tid = threadIdx.x;
  const int w = tid >> 6, lane = tid & 63, quad = lane >> 4, sid = lane & 15;
  const int g = blockIdx.x >> 8, tp = blockIdx.x & 255;
  const int wn = w * 64;

  const int arow = tid >> 3, akc = (tid & 7) << 3;
  const int am = (g * 16 + (arow & 15)) * 512 + 2 * tp + (arow >> 4);
  const float* aptr = &Xf[(size_t)am * 1024 + akc];

#define GX_STAGE(buf, k0)                                                     \
  {                                                                           \
    _Pragma("unroll")                                                         \
    for (int q = 0; q < 8; ++q) {                                             \
      int lin = q * 256 + tid;                                                \
      gl_lds16(Bw + (size_t)(lin >> 3) * 1024 + (k0) + ((lin & 7) << 3),      \
               &Bs[buf][lin << 3]);                                           \
    }                                                                         \
    const float* ap = aptr + (k0);                                            \
    float4 v0 = *(const float4*)ap;                                           \
    float4 v1 = *(const float4*)(ap + 4);                                     \
    s8v p;                                                                    \
    p[0] = f2b(v0.x); p[1] = f2b(v0.y); p[2] = f2b(v0.z); p[3] = f2b(v0.w);   \
    p[4] = f2b(v1.x); p[5] = f2b(v1.y); p[6] = f2b(v1.z); p[7] = f2b(v1.w);   \
    *(s8v*)&As[buf][arow * 72 + akc] = p;                                     \
  }

  f4v acc[2][4];
#pragma unroll
  for (int i = 0; i < 2; ++i)
#pragma unroll
    for (int j = 0; j < 4; ++j) acc[i][j] = (f4v){0.f, 0.f, 0.f, 0.f};

  GX_STAGE(0, 0);
  __syncthreads();
  for (int it = 0; it < 16; ++it) {
    const int cur = it & 1;
    if (it < 15) GX_STAGE(cur ^ 1, (it + 1) * 64);
#pragma unroll
    for (int kb = 0; kb < 2; ++kb) {
      s8v af[2], bf[4];
#pragma unroll
      for (int mt = 0; mt < 2; ++mt)
        af[mt] = *(const s8v*)&As[cur][(16 * mt + sid) * 72 + kb * 32 + quad * 8];
#pragma unroll
      for (int nt = 0; nt < 4; ++nt)
        bf[nt] = *(const s8v*)&Bs[cur][(wn + 16 * nt + sid) * 64 + kb * 32 + quad * 8];
#pragma unroll
      for (int mt = 0; mt < 2; ++mt)
#pragma unroll
        for (int nt = 0; nt < 4; ++nt)
          acc[mt][nt] = __builtin_amdgcn_mfma_f32_16x16x32_bf16(af[mt], bf[nt], acc[mt][nt], 0, 0, 0);
    }
    __syncthreads();
  }
#undef GX_STAGE

  // epilogue: stage C[lr][n] into Ls (pitch 264), then frag-layout contiguous write
  short* Ls = &Bs[0][0];
#pragma unroll
  for (int mt = 0; mt < 2; ++mt)
#pragma unroll
    for (int nt = 0; nt < 4; ++nt) {
      int n = wn + 16 * nt + sid;
#pragma unroll
      for (int r = 0; r < 4; ++r)
        Ls[(16 * mt + 4 * quad + r) * 264 + n] = f2b(acc[mt][nt][r]);
    }
  __syncthreads();
  {
    const size_t obase = (size_t)((g << 9) + 2 * tp) * 4096;
#pragma unroll
    for (int h = 0; h < 2; ++h) {
      int q = h * 256 + tid;            // 0..511
      int tl = q >> 8, q16 = q & 255;
      int ch = q16 >> 3, qq = q16 & 7;
      s4v lo = *(const s4v*)&Ls[(tl * 16 + 2 * qq) * 264 + ch * 4];
      s4v hi = *(const s4v*)&Ls[(tl * 16 + 2 * qq + 1) * 264 + ch * 4];
      s8v v;
      v[0] = lo.x; v[1] = lo.y; v[2] = lo.z; v[3] = lo.w;
      v[4] = hi.x; v[5] = hi.y; v[6] = hi.z; v[7] = hi.w;
      *(s8v*)&C[obase + (size_t)tl * 4096 + q16 * 8] = v;
    }
  }
}

// ---------- layer-0 scan fused with Xc1 = h0 @ A1^T, 8-wave split ----------
// 512 threads: waves 0-3 (grp 0) hold U0 frags and compute h_t; waves 4-7
// (grp 1) hold A1 frags and emit xc1_{t-1}. Both passes run CONCURRENTLY on
// different SIMD slots -> per-step MFMA critical path = ONE 32-MFMA pass (was
// two serialized). Per-wave VGPR ~200 -> (512,2) fits, no spill.
__global__ __launch_bounds__(512, 2) void scan_fuse(const short* __restrict__ Ub,
                                                    const short* __restrict__ A1b,
                                                    const short* __restrict__ XcIn,
                                                    short* __restrict__ XcOut,
                                                    const float* __restrict__ hinit) {
  constexpr int CL = 4, WU = 12, NC = 128;
  __shared__ __align__(16) short hT[2][4096];
  const int tid = threadIdx.x;
  const int w2 = tid >> 6, lane = tid & 63, quad = lane >> 4, sid = lane & 15;
  const int grp = w2 >> 2, wl = w2 & 3;
  const int c = blockIdx.x & (NC - 1);
  const int g = blockIdx.x >> 7;
  const int laneoff = quad * 64 + sid * 4;

  s8v wfr[4][8];                       // grp 0: U0 frags; grp 1: A1 frags
  const short* Wsrc = grp ? A1b : Ub;
#pragma unroll
  for (int mt = 0; mt < 4; ++mt)
#pragma unroll
    for (int kb = 0; kb < 8; ++kb) {
      int i = 64 * wl + 16 * mt + sid;
      int k = 32 * kb + quad * 8;
      wfr[mt][kb] = *(const s8v*)&Wsrc[i * 256 + k];
    }

  const int t0 = (c * CL <= WU) ? 0 : c * CL - WU;
  const int t1 = (c + 1) * CL;

  for (int idx = tid; idx < 4096; idx += 512) {
    int s = idx >> 8, i = idx & 255;
    hT[0][hoff(s, i)] = (t0 == 0) ? f2b(hinit[i]) : (short)0;
  }
  __syncthreads();

  s4v xcn[4] = {};
  if (grp == 0) {
    const size_t xb = (size_t)((g << 9) + t0) * 4096 + 1024 * wl + laneoff;
#pragma unroll
    for (int mt = 0; mt < 4; ++mt)
      xcn[mt] = *(const s4v*)&XcIn[xb + 256 * mt];
  }

  int pr = 0;
  for (int t = t0; t <= t1; ++t) {
    s8v bf[8];                          // h_{t-1} fragments (both groups)
#pragma unroll
    for (int kb = 0; kb < 8; ++kb)
      bf[kb] = *(const s8v*)&hT[pr][kb * 512 + quad * 128 + sid * 8];

    if (grp == 0) {
      const bool doh = (t < t1);
      s4v xcc[4];
      if (doh) {
#pragma unroll
        for (int mt = 0; mt < 4; ++mt) xcc[mt] = xcn[mt];
      }
      if (t + 1 < t1) {   // next step's xc loads in flight under the MFMA pass
        const size_t xb = (size_t)((g << 9) + t + 1) * 4096 + 1024 * wl + laneoff;
#pragma unroll
        for (int mt = 0; mt < 4; ++mt)
          xcn[mt] = *(const s4v*)&XcIn[xb + 256 * mt];
      }
      if (doh) {
        f4v acc[4];
#pragma unroll
        for (int mt = 0; mt < 4; ++mt) acc[mt] = (f4v){0.f, 0.f, 0.f, 0.f};
#pragma unroll
        for (int kb = 0; kb < 8; ++kb)
#pragma unroll
          for (int mt = 0; mt < 4; ++mt)
            acc[mt] = __builtin_amdgcn_mfma_f32_16x16x32_bf16(wfr[mt][kb], bf[kb], acc[mt], 0, 0, 0);
#pragma unroll
        for (int mt = 0; mt < 4; ++mt) {
          int k0 = 64 * wl + 16 * mt + 4 * quad;
          f4v v = acc[mt];
          v.x += b2f(xcc[mt].x); v.y += b2f(xcc[mt].y);
          v.z += b2f(xcc[mt].z); v.w += b2f(xcc[mt].w);
          s4v p; p.x = f2b(v.x); p.y = f2b(v.y); p.z = f2b(v.z); p.w = f2b(v.w);
          *(s4v*)&hT[pr ^ 1][hoff(sid, k0)] = p;
        }
      }
    } else {
      if (t > c * CL) {  // emit xc1_{t-1} = h_{t-1} @ A1^T (owned, warmed rows)
        f4v ax[4];
#pragma unroll
        for (int mt = 0; mt < 4; ++mt) ax[mt] = (f4v){0.f, 0.f, 0.f, 0.f};
#pragma unroll
        for (int kb = 0; kb < 8; ++kb)
#pragma unroll
          for (int mt = 0; mt < 4; ++mt)
            ax[mt] = __builtin_amdgcn_mfma_f32_16x16x32_bf16(wfr[mt][kb], bf[kb], ax[mt], 0, 0, 0);
        const size_t ob = (size_t)((g << 9) + (t - 1)) * 4096 + 1024 * wl + laneoff;
#pragma unroll
        for (int mt = 0; mt < 4; ++mt) {
          s4v p; p.x = f2b(ax[mt].x); p.y = f2b(ax[mt].y);
          p.z = f2b(ax[mt].z); p.w = f2b(ax[mt].w);
          *(s4v*)&XcOut[ob + 256 * mt] = p;
        }
      }
    }
    pr ^= 1;
    lds_barrier();
  }
}

// ---------- chunked recurrence scan (layer 1) ----------
__global__ __launch_bounds__(256, 2) void scan_rnn(const short* __restrict__ Ub,
                                                   const short* __restrict__ XcT,
                                                   short* __restrict__ hbuf,
                                                   const float* __restrict__ hinit) {
  constexpr int CL = 2, WU = 12, NC = 256;
  __shared__ __align__(16) short hT[2][4096];
  const int tid = threadIdx.x;
  const int w = tid >> 6, lane = tid & 63, quad = lane >> 4, sid = lane & 15;
  const int c = blockIdx.x & (NC - 1);
  const int g = blockIdx.x >> 8;
  const int laneoff = quad * 64 + sid * 4;

  s8v uf[4][8];
#pragma unroll
  for (int mt = 0; mt < 4; ++mt)
#pragma unroll
    for (int kb = 0; kb < 8; ++kb) {
      int i = 64 * w + 16 * mt + sid;
      int k = 32 * kb + quad * 8;
      uf[mt][kb] = *(const s8v*)&Ub[i * 256 + k];
    }

  const int t0 = (c * CL <= WU) ? 0 : c * CL - WU;
  const int t1 = (c + 1) * CL;

  for (int idx = tid; idx < 4096; idx += 256) {
    int s = idx >> 8, i = idx & 255;
    hT[0][hoff(s, i)] = (t0 == 0) ? f2b(hinit[i]) : (short)0;
  }
  __syncthreads();

  s4v xcn[4];
  {
    const size_t xb = (size_t)((g << 9) + t0) * 4096 + 1024 * w + laneoff;
#pragma unroll
    for (int mt = 0; mt < 4; ++mt)
      xcn[mt] = *(const s4v*)&XcT[xb + 256 * mt];
  }

  int pr = 0;
  for (int t = t0; t < t1; ++t) {
    s8v bf[8];
#pragma unroll
    for (int kb = 0; kb < 8; ++kb)
      bf[kb] = *(const s8v*)&hT[pr][kb * 512 + quad * 128 + sid * 8];
    s4v xcc[4];
#pragma unroll
    for (int mt = 0; mt < 4; ++mt) xcc[mt] = xcn[mt];
    if (t + 1 < t1) {
      const size_t xb = (size_t)((g << 9) + t + 1) * 4096 + 1024 * w + laneoff;
#pragma unroll
      for (int mt = 0; mt < 4; ++mt)
        xcn[mt] = *(const s4v*)&XcT[xb + 256 * mt];
    }

    f4v acc[4];
#pragma unroll
    for (int mt = 0; mt < 4; ++mt) acc[mt] = (f4v){0.f, 0.f, 0.f, 0.f};
#pragma unroll
    for (int kb = 0; kb < 8; ++kb)
#pragma unroll
      for (int mt = 0; mt < 4; ++mt)
        acc[mt] = __builtin_amdgcn_mfma_f32_16x16x32_bf16(uf[mt][kb], bf[kb], acc[mt], 0, 0, 0);

    const bool emit = (t >= c * CL);
    const size_t xbase = ((size_t)((g << 9) + t) * 16 + sid) * 256;
#pragma unroll
    for (int mt = 0; mt < 4; ++mt) {
      int k0 = 64 * w + 16 * mt + 4 * quad;
      f4v v = acc[mt];
      v.x += b2f(xcc[mt].x); v.y += b2f(xcc[mt].y);
      v.z += b2f(xcc[mt].z); v.w += b2f(xcc[mt].w);
      s4v p; p.x = f2b(v.x); p.y = f2b(v.y); p.z = f2b(v.z); p.w = f2b(v.w);
      *(s4v*)&hT[pr ^ 1][hoff(sid, k0)] = p;
      if (emit) *(s4v*)&hbuf[xbase + k0] = p;
    }
    pr ^= 1;
    lds_barrier();
  }
}

// ---------- fused logits GEMM + softmax over T ----------
__global__ __launch_bounds__(256, 2) void gemm_logsm(const short* __restrict__ A,
                                                     const short* __restrict__ Bw,
                                                     float* __restrict__ out) {
  __shared__ __align__(16) short As[512 * 40];   // [t][k-local 32, pitch 40]
  __shared__ __align__(16) short Bs[64 * 32];
  __shared__ float2 red[4][64];
  const int tid = threadIdx.x;
  const int w = tid >> 6, lane = tid & 63, quad = lane >> 4, sid = lane & 15;
  const int b = blockIdx.x & 31, ot = blockIdx.x >> 5;
  const int g = b >> 4, si = b & 15;

  f4v acc[8][4];
#pragma unroll
  for (int i = 0; i < 8; ++i)
#pragma unroll
    for (int j = 0; j < 4; ++j) acc[i][j] = (f4v){0.f, 0.f, 0.f, 0.f};

  const int brow = tid & 63, bkch = tid >> 6;
  const short* bptr = Bw + (size_t)(ot * 64 + brow) * 256 + bkch * 8;

  s8v va[8], vb;
#pragma unroll
  for (int q = 0; q < 8; ++q) {
    int lin = q * 256 + tid;
    int t = lin >> 2, kch = lin & 3;
    size_t ar = ((size_t)(g * 512 + t) * 16 + si) * 256;
    va[q] = *(const s8v*)(A + ar + kch * 8);
  }
  vb = *(const s8v*)bptr;

  for (int it = 0; it < 8; ++it) {
#pragma unroll
    for (int q = 0; q < 8; ++q) {
      int lin = q * 256 + tid;
      int t = lin >> 2, kch = lin & 3;
      *(s8v*)&As[t * 40 + kch * 8] = va[q];
    }
    *(s8v*)&Bs[tid << 3] = vb;
    __syncthreads();
    if (it < 7) {   // issue next k-step's loads; land during the MFMA phase
      int k0n = (it + 1) * 32;
#pragma unroll
      for (int q = 0; q < 8; ++q) {
        int lin = q * 256 + tid;
        int t = lin >> 2, kch = lin & 3;
        size_t ar = ((size_t)(g * 512 + t) * 16 + si) * 256;
        va[q] = *(const s8v*)(A + ar + k0n + kch * 8);
      }
      vb = *(const s8v*)(bptr + k0n);
    }
    s8v bf[4];
#pragma unroll
    for (int nt = 0; nt < 4; ++nt)
      bf[nt] = *(const s8v*)&Bs[(quad * 64 + 16 * nt + sid) * 8];
#pragma unroll
    for (int mt = 0; mt < 8; ++mt) {
      s8v af = *(const s8v*)&As[(128 * w + 16 * mt + sid) * 40 + quad * 8];
#pragma unroll
      for (int nt = 0; nt < 4; ++nt)
        acc[mt][nt] = __builtin_amdgcn_mfma_f32_16x16x32_bf16(af, bf[nt], acc[mt][nt], 0, 0, 0);
    }
    __syncthreads();
  }

  // softmax stats over t per column (16nt+sid)
  float Mv[4], Iv[4];
#pragma unroll
  for (int nt = 0; nt < 4; ++nt) {
    float m = -3.0e38f;
#pragma unroll
    for (int mt = 0; mt < 8; ++mt)
#pragma unroll
      for (int r = 0; r < 4; ++r) m = fmaxf(m, acc[mt][nt][r]);
    float sum = 0.f;
#pragma unroll
    for (int mt = 0; mt < 8; ++mt)
#pragma unroll
      for (int r = 0; r < 4; ++r) sum += __expf(acc[mt][nt][r] - m);
#pragma unroll
    for (int d = 16; d < 64; d <<= 1) {
      float om = __shfl_xor(m, d, 64);
      float os = __shfl_xor(sum, d, 64);
      float nm = fmaxf(m, om);
      sum = sum * __expf(m - nm) + os * __expf(om - nm);
      m = nm;
    }
    if (quad == 0) red[w][16 * nt + sid] = (float2){m, sum};
  }
  __syncthreads();
#pragma unroll
  for (int nt = 0; nt < 4; ++nt) {
    float M = -3.0e38f, S = 0.f;
#pragma unroll
    for (int ww = 0; ww < 4; ++ww) {
      float2 r2 = red[ww][16 * nt + sid];
      float nm = fmaxf(M, r2.x);
      S = S * __expf(M - nm) + r2.y * __expf(r2.x - nm);
      M = nm;
    }
    Mv[nt] = M;
    Iv[nt] = 1.0f / S;
  }

  // direct scattered out-write (no barriers, no LDS round-trip)
  const size_t cbase = (size_t)b * 524288 + ot * 64 + sid;
#pragma unroll
  for (int nt = 0; nt < 4; ++nt) {
    const size_t cb = cbase + 16 * nt;
#pragma unroll
    for (int mt = 0; mt < 8; ++mt)
#pragma unroll
      for (int r = 0; r < 4; ++r) {
        int t = 128 * w + 16 * mt + 4 * quad + r;
        out[cb + (size_t)t * 1024] = __expf(acc[mt][nt][r] - Mv[nt]) * Iv[nt];
      }
  }
}

// ---------- host ----------
extern "C" void kernel_launch(void* const* d_in, const int* in_sizes, int n_in,
                              void* d_out, int out_size, void* d_ws, size_t ws_size,
                              hipStream_t stream) {
  (void)in_sizes; (void)n_in; (void)out_size; (void)ws_size;
  const float* xf   = (const float*)d_in[0];
  const float* hs   = (const float*)d_in[1];
  const float* wemb = (const float*)d_in[2];
  const float* wf   = (const float*)d_in[3];
  const float* ufp  = (const float*)d_in[4];
  const float* vfp  = (const float*)d_in[5];
  const float* wout = (const float*)d_in[6];

  char* ws = (char*)d_ws;
  short* hbuf = (short*)(ws);              // 8,388,608 B  layer-1 h, row layout
  short* xcT0 = (short*)(ws + 8388608);    // 8,388,608 B  Xc0 frag layout
  short* xcT1 = (short*)(ws + 16777216);   // 8,388,608 B  Xc1 frag layout
  short* a0   = (short*)(ws + 25165824);   //   524,288 B  W0@Wemb  [256,1024]
  short* a1   = (short*)(ws + 25690112);   //   131,072 B  W1@V0    [256,256]
  short* a2   = (short*)(ws + 25821184);   //   524,288 B  Wout@V1  [1024,256]
  short* ub   = (short*)(ws + 26345472);   //   262,144 B  U bf16 (2 layers)

  // a0/a1/a2 from f32 inputs + U -> bf16
  wgemm<<<40, 256, 0, stream>>>(wemb, wf, vfp, wout, ufp, a0, a1, a2, ub);

  // Xc0 = x(f32) @ a0^T -> frag layout (2-phase pipelined)
  gemm_x<<<512, 256, 0, stream>>>(xf, a0, xcT0);

  // layer-0 scan, Xc1 = h0 @ a1^T fused; 8-wave split (parallel passes)
  scan_fuse<<<256, 512, 0, stream>>>(ub, a1, xcT0, xcT1, hs);

  // layer-1 scan (frag in, row out)
  scan_rnn<<<512, 256, 0, stream>>>(ub + 65536, xcT1, hbuf, hs + 256);

  // probs = softmax_T(h1 @ a2^T), fused, reg-prefetch staging
  gemm_logsm<<<512, 256, 0, stream>>>(hbuf, a2, (float*)d_out);
}